// Round 3
// baseline (549.154 us; speedup 1.0000x reference)
//
#include <hip/hip_runtime.h>
#include <hip/hip_bf16.h>

#define DELTA_VAR  0.5f
#define DELTA_DIST 1.5f
#define ALPHA 1.0f
#define BETA  1.0f
#define GAMMA 0.001f

constexpr int N = 2;
constexpr int E = 16;
constexpr int C = 16;
constexpr int V = 64 * 128 * 128;   // 1048576 voxels per batch
constexpr int NBANK = 8;            // shadow banks to spread atomic chains
constexpr int B1 = 1024;            // pass1 blocks per n (4096 waves/n, 256 voxels/wave)
constexpr int B2 = 1024;            // pass2 blocks per n (1 float4 per thread)

// workspace layout (floats)
constexpr int OFF_CNT = 0;                        // NBANK*N*C      = 256
constexpr int OFF_SUM = OFF_CNT + NBANK * N * C;  // NBANK*N*C*E    = 4096
constexpr int OFF_MT  = OFF_SUM + NBANK * N * C * E;  // means^T (n,e,c) = 512
constexpr int OFF_INV = OFF_MT + N * E * C;       // 1/count        = 32
constexpr int OFF_DR  = OFF_INV + N * C;          // dist[2], reg[2] = 4
constexpr int OFF_VAR = OFF_DR + 4;               // NBANK*N        = 16
constexpr int OFF_CTR = OFF_VAR + NBANK * N;      // 2 ints (tickets)
constexpr int WS_FLOATS = OFF_CTR + 2;

typedef __attribute__((ext_vector_type(8))) short bf16x8;
typedef __attribute__((ext_vector_type(4))) float f32x4;

__device__ __forceinline__ float ws_ld(const float* p) {
    return __hip_atomic_load(p, __ATOMIC_RELAXED, __HIP_MEMORY_SCOPE_AGENT);
}
__device__ __forceinline__ short f2bf(float f) {
    return __builtin_bit_cast(short, __float2bfloat16(f));
}

__global__ void zero_ws(float* __restrict__ ws) {
    const int i = blockIdx.x * 256 + threadIdx.x;
    if (i < WS_FLOATS) ws[i] = 0.0f;
}

// Pass 1 (MFMA): sums[c][e] = onehot[C][V] x X^T[V][E] via 16x16x32 bf16 MFMA.
// Each wave owns a contiguous 256-voxel span (8 chunks of 32), dual
// accumulators break the MFMA dependency chain. Last block (device ticket)
// computes means (+transposed copy), inv counts, distance & reg terms.
__global__ __launch_bounds__(256, 4) void pass1_mfma(
    const float* __restrict__ x, const int* __restrict__ t, float* __restrict__ ws) {
    const int n    = blockIdx.y;
    const int tid  = threadIdx.x;
    const int lane = tid & 63;
    const int wave = blockIdx.x * 4 + (tid >> 6);   // [0, 4096)
    const int col  = lane & 15;                      // A row (=cluster) & B col (=e)
    const int kc   = lane >> 4;                      // k-chunk within K=32

    const float* __restrict__ xp =
        x + (size_t)n * E * V + (size_t)col * V + wave * 256 + kc * 8;
    const int* __restrict__ tp = t + (size_t)n * V + wave * 256 + kc * 8;

    f32x4 acc0 = {0.f, 0.f, 0.f, 0.f}, acc1 = {0.f, 0.f, 0.f, 0.f};
    int cnt = 0;
    const short ONE = (short)0x3F80;                 // bf16 1.0

#pragma unroll
    for (int j = 0; j < 8; ++j) {
        const float4 x0 = *reinterpret_cast<const float4*>(xp + j * 32);
        const float4 x1 = *reinterpret_cast<const float4*>(xp + j * 32 + 4);
        const int4   t0 = *reinterpret_cast<const int4*>(tp + j * 32);
        const int4   t1 = *reinterpret_cast<const int4*>(tp + j * 32 + 4);

        bf16x8 bfrag;
        bfrag[0] = f2bf(x0.x); bfrag[1] = f2bf(x0.y);
        bfrag[2] = f2bf(x0.z); bfrag[3] = f2bf(x0.w);
        bfrag[4] = f2bf(x1.x); bfrag[5] = f2bf(x1.y);
        bfrag[6] = f2bf(x1.z); bfrag[7] = f2bf(x1.w);

        bf16x8 afrag;
        afrag[0] = (t0.x == col) ? ONE : (short)0; cnt += (t0.x == col);
        afrag[1] = (t0.y == col) ? ONE : (short)0; cnt += (t0.y == col);
        afrag[2] = (t0.z == col) ? ONE : (short)0; cnt += (t0.z == col);
        afrag[3] = (t0.w == col) ? ONE : (short)0; cnt += (t0.w == col);
        afrag[4] = (t1.x == col) ? ONE : (short)0; cnt += (t1.x == col);
        afrag[5] = (t1.y == col) ? ONE : (short)0; cnt += (t1.y == col);
        afrag[6] = (t1.z == col) ? ONE : (short)0; cnt += (t1.z == col);
        afrag[7] = (t1.w == col) ? ONE : (short)0; cnt += (t1.w == col);

        if (j & 1) acc1 = __builtin_amdgcn_mfma_f32_16x16x32_bf16(afrag, bfrag, acc1, 0, 0, 0);
        else       acc0 = __builtin_amdgcn_mfma_f32_16x16x32_bf16(afrag, bfrag, acc0, 0, 0, 0);
    }
    const f32x4 acc = acc0 + acc1;
    cnt += __shfl_down(cnt, 32);
    cnt += __shfl_down(cnt, 16);   // lanes 0..15: per-cluster counts

    __shared__ float s_sums[C * E];
    __shared__ float s_cnt[C];
    if (tid < C * E) s_sums[tid] = 0.0f;
    if (tid < C)     s_cnt[tid] = 0.0f;
    __syncthreads();
#pragma unroll
    for (int r = 0; r < 4; ++r)
        atomicAdd(&s_sums[(kc * 4 + r) * E + col], acc[r]);  // row=kc*4+r (m89 C/D map)
    if (lane < C) atomicAdd(&s_cnt[lane], (float)cnt);
    __syncthreads();

    const int bank = blockIdx.x & (NBANK - 1);
    if (tid < C * E) atomicAdd(&ws[OFF_SUM + (bank * N + n) * C * E + tid], s_sums[tid]);
    if (tid < C)     atomicAdd(&ws[OFF_CNT + (bank * N + n) * C + tid], s_cnt[tid]);

    // ---- device ticket: last block finalizes means/dist/reg ----
    __threadfence();
    __shared__ int s_last;
    if (tid == 0)
        s_last = (atomicAdd((int*)&ws[OFF_CTR], 1) == (int)(gridDim.x * gridDim.y) - 1);
    __syncthreads();
    if (!s_last) return;
    __threadfence();

    __shared__ float f_m[N * C * E];
    __shared__ float f_c[N * C];
    if (tid < N * C) {
        float s = 0.0f;
#pragma unroll
        for (int b = 0; b < NBANK; ++b)
            s += ws_ld(&ws[OFF_CNT + b * N * C + tid]);
        f_c[tid] = s;
        ws[OFF_INV + tid] = 1.0f / s;
    }
    __syncthreads();
    for (int idx = tid; idx < N * C * E; idx += 256) {
        float s = 0.0f;
#pragma unroll
        for (int b = 0; b < NBANK; ++b)
            s += ws_ld(&ws[OFF_SUM + b * N * C * E + idx]);
        const float m = s / f_c[idx >> 4];
        f_m[idx] = m;
        const int nn = idx >> 8, cc = (idx >> 4) & 15, ee = idx & 15;
        ws[OFF_MT + nn * E * C + ee * C + cc] = m;     // transposed for pass2
    }
    __shared__ float f_dr[4];                           // dist[2], reg[2]
    if (tid < 4) f_dr[tid] = 0.0f;
    __syncthreads();
#pragma unroll
    for (int it = 0; it < 2; ++it) {
        const int pair = it * 256 + tid;                // (n, i, j)
        const int nn = pair >> 8, i = (pair >> 4) & 15, jj = pair & 15;
        const float* mi = &f_m[(nn * C + i) * E];
        const float* mj = &f_m[(nn * C + jj) * E];
        if (i != jj) {
            float d2 = 0.0f;
#pragma unroll
            for (int e = 0; e < E; ++e) { const float df = mi[e] - mj[e]; d2 = fmaf(df, df, d2); }
            const float hd = 2.0f * DELTA_DIST - sqrtf(d2);
            if (hd > 0.0f) atomicAdd(&f_dr[nn], hd * hd);
        } else {
            float s2 = 0.0f;
#pragma unroll
            for (int e = 0; e < E; ++e) s2 = fmaf(mi[e], mi[e], s2);
            atomicAdd(&f_dr[2 + nn], sqrtf(s2));
        }
    }
    __syncthreads();
    if (tid < 2)      ws[OFF_DR + tid] = f_dr[tid] * (1.0f / (C * (C - 1)));
    else if (tid < 4) ws[OFF_DR + tid] = f_dr[tid] * (1.0f / C);
}

// Pass 2: hinged distance of each voxel to its own cluster mean, weighted by
// 1/count at accumulation time (Sum_c var_c/cnt_c == Sum_v h_v/cnt_{t_v}).
// One float4 of voxels per thread. Last block (ticket) emits the scalar loss.
__global__ __launch_bounds__(256, 4) void pass2_var(
    const float* __restrict__ x, const int* __restrict__ t,
    float* __restrict__ ws, float* __restrict__ out) {
    const int n = blockIdx.y;
    const int tid = threadIdx.x;
    __shared__ float s_mt[E * C];   // [e][c] — 16-bank window per e, broadcast-ish
    __shared__ float s_inv[C];
    s_mt[tid] = ws[OFF_MT + n * E * C + tid];
    if (tid < C) s_inv[tid] = ws[OFF_INV + n * C + tid];
    __syncthreads();

    const int i = blockIdx.x * 256 + tid;
    const int4 tv = reinterpret_cast<const int4*>(t + (size_t)n * V)[i];
    const float* xb = x + (size_t)n * E * V + (size_t)i * 4;
    float d0 = 0.f, d1 = 0.f, d2 = 0.f, d3 = 0.f;
#pragma unroll
    for (int e = 0; e < E; ++e) {
        const float4 xv = *reinterpret_cast<const float4*>(xb + (size_t)e * V);
        const float* mte = &s_mt[e * C];
        float u;
        u = xv.x - mte[tv.x]; d0 = fmaf(u, u, d0);
        u = xv.y - mte[tv.y]; d1 = fmaf(u, u, d1);
        u = xv.z - mte[tv.z]; d2 = fmaf(u, u, d2);
        u = xv.w - mte[tv.w]; d3 = fmaf(u, u, d3);
    }
    float h0 = sqrtf(d0) - DELTA_VAR; h0 = (h0 > 0.f) ? h0 * h0 : 0.f;
    float h1 = sqrtf(d1) - DELTA_VAR; h1 = (h1 > 0.f) ? h1 * h1 : 0.f;
    float h2 = sqrtf(d2) - DELTA_VAR; h2 = (h2 > 0.f) ? h2 * h2 : 0.f;
    float h3 = sqrtf(d3) - DELTA_VAR; h3 = (h3 > 0.f) ? h3 * h3 : 0.f;
    float a = h0 * s_inv[tv.x] + h1 * s_inv[tv.y] + h2 * s_inv[tv.z] + h3 * s_inv[tv.w];

#pragma unroll
    for (int off = 32; off; off >>= 1) a += __shfl_down(a, off);
    __shared__ float s_blk;
    if (tid == 0) s_blk = 0.0f;
    __syncthreads();
    if ((tid & 63) == 0) atomicAdd(&s_blk, a);
    __syncthreads();
    if (tid == 0)
        atomicAdd(&ws[OFF_VAR + (blockIdx.x & (NBANK - 1)) * N + n], s_blk);

    // ---- device ticket: last block combines the scalar loss ----
    __threadfence();
    __shared__ int s_last;
    if (tid == 0)
        s_last = (atomicAdd((int*)&ws[OFF_CTR] + 1, 1) == (int)(gridDim.x * gridDim.y) - 1);
    __syncthreads();
    if (!s_last) return;
    __threadfence();
    if (tid == 0) {
        float loss = 0.0f;
#pragma unroll
        for (int nn = 0; nn < N; ++nn) {
            float v = 0.0f;
#pragma unroll
            for (int b = 0; b < NBANK; ++b) v += ws_ld(&ws[OFF_VAR + b * N + nn]);
            loss += ALPHA * (v * (1.0f / C)) + BETA * ws[OFF_DR + nn] + GAMMA * ws[OFF_DR + 2 + nn];
        }
        out[0] = loss * (1.0f / N);
    }
}

extern "C" void kernel_launch(void* const* d_in, const int* in_sizes, int n_in,
                              void* d_out, int out_size, void* d_ws, size_t ws_size,
                              hipStream_t stream) {
    const float* x = (const float*)d_in[0];
    const int*   t = (const int*)d_in[1];
    float* ws  = (float*)d_ws;
    float* out = (float*)d_out;

    hipLaunchKernelGGL(zero_ws, dim3((WS_FLOATS + 255) / 256), dim3(256), 0, stream, ws);
    hipLaunchKernelGGL(pass1_mfma, dim3(B1, N), dim3(256), 0, stream, x, t, ws);
    hipLaunchKernelGGL(pass2_var, dim3(B2, N), dim3(256), 0, stream, x, t, ws, out);
}

// Round 5
// 73.889 us; speedup vs baseline: 7.4321x; 7.4321x over previous
//
#include <hip/hip_runtime.h>
#include <hip/hip_bf16.h>

#define DELTA_VAR  0.5f
#define DELTA_DIST 1.5f
#define ALPHA 1.0f
#define BETA  1.0f
#define GAMMA 0.001f

constexpr int N = 2;
constexpr int E = 16;
constexpr int C = 16;
constexpr int V = 64 * 128 * 128;   // 1048576 voxels per batch
constexpr int NBANK = 8;            // shadow banks to spread atomic chains
constexpr int B1 = 1024;            // pass1 blocks per n (4096 waves/n, 256 voxels/wave)
constexpr int B2 = 1024;            // pass2 blocks per n (1 float4 per thread)

// workspace layout (floats)
constexpr int OFF_CNT = 0;                            // NBANK*N*C   = 256
constexpr int OFF_SUM = OFF_CNT + NBANK * N * C;      // NBANK*N*C*E = 4096
constexpr int OFF_MT  = OFF_SUM + NBANK * N * C * E;  // means^T (n,e,c) = 512
constexpr int OFF_INV = OFF_MT + N * E * C;           // 1/count = 32
constexpr int OFF_DR  = OFF_INV + N * C;              // dist[2], reg[2] = 4
constexpr int OFF_VAR = OFF_DR + 4;                   // NBANK*N = 16
constexpr int WS_FLOATS = OFF_VAR + NBANK * N;        // 4916

typedef __attribute__((ext_vector_type(8))) short bf16x8;
typedef __attribute__((ext_vector_type(4))) float f32x4;

__device__ __forceinline__ short f2bf(float f) {
    return __builtin_bit_cast(short, __float2bfloat16(f));
}

__global__ void zero_ws(float* __restrict__ ws) {
    const int i = blockIdx.x * 256 + threadIdx.x;
    if (i < WS_FLOATS) ws[i] = 0.0f;
}

// Pass 1 (MFMA): sums[c][e] = onehot[C][V] x X^T[V][E] via 16x16x32 bf16 MFMA.
// ROUND-3-PROVEN BODY (absmax 0.0): each wave owns a contiguous 256-voxel
// span (8 chunks of 32), dual accumulators break the MFMA dependency chain.
// No fences, no tickets (round 3's fence storm removed).
__global__ __launch_bounds__(256, 4) void pass1_mfma(
    const float* __restrict__ x, const int* __restrict__ t, float* __restrict__ ws) {
    const int n    = blockIdx.y;
    const int tid  = threadIdx.x;
    const int lane = tid & 63;
    const int wave = blockIdx.x * 4 + (tid >> 6);   // [0, 4096)
    const int col  = lane & 15;                      // A row (=cluster) & B col (=e)
    const int kc   = lane >> 4;                      // k-chunk within K=32

    const float* __restrict__ xp =
        x + (size_t)n * E * V + (size_t)col * V + wave * 256 + kc * 8;
    const int* __restrict__ tp = t + (size_t)n * V + wave * 256 + kc * 8;

    f32x4 acc0 = {0.f, 0.f, 0.f, 0.f}, acc1 = {0.f, 0.f, 0.f, 0.f};
    int cnt = 0;
    const short ONE = (short)0x3F80;                 // bf16 1.0

#pragma unroll
    for (int j = 0; j < 8; ++j) {
        const float4 x0 = *reinterpret_cast<const float4*>(xp + j * 32);
        const float4 x1 = *reinterpret_cast<const float4*>(xp + j * 32 + 4);
        const int4   t0 = *reinterpret_cast<const int4*>(tp + j * 32);
        const int4   t1 = *reinterpret_cast<const int4*>(tp + j * 32 + 4);

        bf16x8 bfrag;
        bfrag[0] = f2bf(x0.x); bfrag[1] = f2bf(x0.y);
        bfrag[2] = f2bf(x0.z); bfrag[3] = f2bf(x0.w);
        bfrag[4] = f2bf(x1.x); bfrag[5] = f2bf(x1.y);
        bfrag[6] = f2bf(x1.z); bfrag[7] = f2bf(x1.w);

        bf16x8 afrag;
        afrag[0] = (t0.x == col) ? ONE : (short)0; cnt += (t0.x == col);
        afrag[1] = (t0.y == col) ? ONE : (short)0; cnt += (t0.y == col);
        afrag[2] = (t0.z == col) ? ONE : (short)0; cnt += (t0.z == col);
        afrag[3] = (t0.w == col) ? ONE : (short)0; cnt += (t0.w == col);
        afrag[4] = (t1.x == col) ? ONE : (short)0; cnt += (t1.x == col);
        afrag[5] = (t1.y == col) ? ONE : (short)0; cnt += (t1.y == col);
        afrag[6] = (t1.z == col) ? ONE : (short)0; cnt += (t1.z == col);
        afrag[7] = (t1.w == col) ? ONE : (short)0; cnt += (t1.w == col);

        if (j & 1) acc1 = __builtin_amdgcn_mfma_f32_16x16x32_bf16(afrag, bfrag, acc1, 0, 0, 0);
        else       acc0 = __builtin_amdgcn_mfma_f32_16x16x32_bf16(afrag, bfrag, acc0, 0, 0, 0);
    }
    const f32x4 acc = acc0 + acc1;
    cnt += __shfl_down(cnt, 32);
    cnt += __shfl_down(cnt, 16);   // lanes 0..15: per-cluster counts

    __shared__ float s_sums[C * E];
    __shared__ float s_cnt[C];
    if (tid < C * E) s_sums[tid] = 0.0f;
    if (tid < C)     s_cnt[tid] = 0.0f;
    __syncthreads();
#pragma unroll
    for (int r = 0; r < 4; ++r)
        atomicAdd(&s_sums[(kc * 4 + r) * E + col], acc[r]);  // row=kc*4+r (m89 C/D map)
    if (lane < C) atomicAdd(&s_cnt[lane], (float)cnt);
    __syncthreads();

    const int bank = blockIdx.x & (NBANK - 1);
    if (tid < C * E) atomicAdd(&ws[OFF_SUM + (bank * N + n) * C * E + tid], s_sums[tid]);
    if (tid < C)     atomicAdd(&ws[OFF_CNT + (bank * N + n) * C + tid], s_cnt[tid]);
}

// Means (+transposed copy), inverse counts, distance & regularizer terms.
// 1 block, 256 threads. (= round 3's ticket body with plain loads.)
__global__ void finalize_means(float* __restrict__ ws) {
    const int tid = threadIdx.x;
    __shared__ float f_m[N * C * E];
    __shared__ float f_c[N * C];
    __shared__ float f_dr[4];
    if (tid < N * C) {
        float s = 0.0f;
#pragma unroll
        for (int b = 0; b < NBANK; ++b) s += ws[OFF_CNT + b * N * C + tid];
        f_c[tid] = s;
        ws[OFF_INV + tid] = 1.0f / s;
    }
    if (tid < 4) f_dr[tid] = 0.0f;
    __syncthreads();
    for (int idx = tid; idx < N * C * E; idx += 256) {
        float s = 0.0f;
#pragma unroll
        for (int b = 0; b < NBANK; ++b) s += ws[OFF_SUM + b * N * C * E + idx];
        const float m = s / f_c[idx >> 4];
        f_m[idx] = m;
        const int nn = idx >> 8, cc = (idx >> 4) & 15, ee = idx & 15;
        ws[OFF_MT + nn * E * C + ee * C + cc] = m;  // transposed for pass2
    }
    __syncthreads();
    for (int pair = tid; pair < N * C * C; pair += 256) {
        const int nn = pair >> 8, i = (pair >> 4) & 15, jj = pair & 15;
        const float* mi = &f_m[(nn * C + i) * E];
        const float* mj = &f_m[(nn * C + jj) * E];
        if (i != jj) {
            float d2 = 0.0f;
#pragma unroll
            for (int e = 0; e < E; ++e) { const float df = mi[e] - mj[e]; d2 = fmaf(df, df, d2); }
            const float hd = 2.0f * DELTA_DIST - sqrtf(d2);
            if (hd > 0.0f) atomicAdd(&f_dr[nn], hd * hd);
        } else {
            float s2 = 0.0f;
#pragma unroll
            for (int e = 0; e < E; ++e) s2 = fmaf(mi[e], mi[e], s2);
            atomicAdd(&f_dr[2 + nn], sqrtf(s2));
        }
    }
    __syncthreads();
    if (tid < 2)      ws[OFF_DR + tid] = f_dr[tid] * (1.0f / (C * (C - 1)));
    else if (tid < 4) ws[OFF_DR + tid] = f_dr[tid] * (1.0f / C);
}

// Pass 2 (round-3-proven body): hinged distance of each voxel to its own
// cluster mean, weighted by 1/count at accumulation time
// (Sum_c var_c/cnt_c == Sum_v h_v/cnt_{t_v}). One float4 per thread.
__global__ __launch_bounds__(256, 4) void pass2_var(
    const float* __restrict__ x, const int* __restrict__ t, float* __restrict__ ws) {
    const int n = blockIdx.y;
    const int tid = threadIdx.x;
    __shared__ float s_mt[E * C];   // [e][c]
    __shared__ float s_inv[C];
    s_mt[tid] = ws[OFF_MT + n * E * C + tid];
    if (tid < C) s_inv[tid] = ws[OFF_INV + n * C + tid];
    __syncthreads();

    const int i = blockIdx.x * 256 + tid;
    const int4 tv = reinterpret_cast<const int4*>(t + (size_t)n * V)[i];
    const float* xb = x + (size_t)n * E * V + (size_t)i * 4;
    float d0 = 0.f, d1 = 0.f, d2 = 0.f, d3 = 0.f;
#pragma unroll
    for (int e = 0; e < E; ++e) {
        const float4 xv = *reinterpret_cast<const float4*>(xb + (size_t)e * V);
        const float* mte = &s_mt[e * C];
        float u;
        u = xv.x - mte[tv.x]; d0 = fmaf(u, u, d0);
        u = xv.y - mte[tv.y]; d1 = fmaf(u, u, d1);
        u = xv.z - mte[tv.z]; d2 = fmaf(u, u, d2);
        u = xv.w - mte[tv.w]; d3 = fmaf(u, u, d3);
    }
    float h0 = sqrtf(d0) - DELTA_VAR; h0 = (h0 > 0.f) ? h0 * h0 : 0.f;
    float h1 = sqrtf(d1) - DELTA_VAR; h1 = (h1 > 0.f) ? h1 * h1 : 0.f;
    float h2 = sqrtf(d2) - DELTA_VAR; h2 = (h2 > 0.f) ? h2 * h2 : 0.f;
    float h3 = sqrtf(d3) - DELTA_VAR; h3 = (h3 > 0.f) ? h3 * h3 : 0.f;
    float a = h0 * s_inv[tv.x] + h1 * s_inv[tv.y] + h2 * s_inv[tv.z] + h3 * s_inv[tv.w];

#pragma unroll
    for (int off = 32; off; off >>= 1) a += __shfl_down(a, off);
    __shared__ float s_blk;
    if (tid == 0) s_blk = 0.0f;
    __syncthreads();
    if ((tid & 63) == 0) atomicAdd(&s_blk, a);
    __syncthreads();
    if (tid == 0)
        atomicAdd(&ws[OFF_VAR + (blockIdx.x & (NBANK - 1)) * N + n], s_blk);
}

// Combine the scalar loss. Deliberately serial — 16+4 reads, 1 thread.
__global__ void final_loss(const float* __restrict__ ws, float* __restrict__ out) {
    if (threadIdx.x != 0) return;
    float v[N] = {0.0f, 0.0f};
    for (int b = 0; b < NBANK; ++b)
        for (int nn = 0; nn < N; ++nn) v[nn] += ws[OFF_VAR + b * N + nn];
    float loss = 0.0f;
    for (int nn = 0; nn < N; ++nn)
        loss += ALPHA * (v[nn] * (1.0f / C))
              + BETA * ws[OFF_DR + nn]
              + GAMMA * ws[OFF_DR + 2 + nn];
    out[0] = loss * (1.0f / N);
}

extern "C" void kernel_launch(void* const* d_in, const int* in_sizes, int n_in,
                              void* d_out, int out_size, void* d_ws, size_t ws_size,
                              hipStream_t stream) {
    const float* x = (const float*)d_in[0];
    const int*   t = (const int*)d_in[1];
    float* ws  = (float*)d_ws;
    float* out = (float*)d_out;

    hipLaunchKernelGGL(zero_ws, dim3((WS_FLOATS + 255) / 256), dim3(256), 0, stream, ws);
    hipLaunchKernelGGL(pass1_mfma, dim3(B1, N), dim3(256), 0, stream, x, t, ws);
    hipLaunchKernelGGL(finalize_means, dim3(1), dim3(256), 0, stream, ws);
    hipLaunchKernelGGL(pass2_var, dim3(B2, N), dim3(256), 0, stream, x, t, ws);
    hipLaunchKernelGGL(final_loss, dim3(1), dim3(64), 0, stream, ws, out);
}